// Round 8
// baseline (142.414 us; speedup 1.0000x reference)
//
#include <hip/hip_runtime.h>
#include <math.h>

#define NTOK   16384
#define DIM    2048
#define NEXP   64
#define TOPK   8
#define TB     32          // tokens per block
#define KC     64          // K chunk
#define NCHUNK (DIM / KC)  // 32

typedef double v4d __attribute__((ext_vector_type(4)));

// ---- single fused kernel: barrier-free f64-MFMA main loop, global->reg direct ----
__global__ __launch_bounds__(256, 2) void router_kernel(
    const float* __restrict__ x, const float* __restrict__ proto,
    float* __restrict__ out)
{
    __shared__ float  logits[TB][NEXP];   // 8 KiB
    __shared__ double xinv_lds[TB];
    __shared__ double pinv_lds[NEXP];

    const int tid  = threadIdx.x;
    const int lane = tid & 63;
    const int w    = tid >> 6;            // wave 0..3
    const int tok0 = blockIdx.x * TB;

    // MFMA tile assignment: wave = (ttile, epair); lane = (akg quarter, arow)
    const int ttile = w & 1;
    const int epair = w >> 1;
    const int arow  = lane & 15;          // A-row / B-col label
    const int akg   = lane >> 4;          // quarter-wave k-group
    const int kbase = akg * 16;           // lane's private 16-k segment (r6/r7 verified)

    // ---- layout calibration (verified r4): (lane,reg) -> (row,col) ----
    v4d c1 = {0., 0., 0., 0.}, c2 = {0., 0., 0., 0.};
    c1 = __builtin_amdgcn_mfma_f64_16x16x4f64((double)arow, 1.0, c1, 0, 0, 0);
    c2 = __builtin_amdgcn_mfma_f64_16x16x4f64(1.0, (double)arow, c2, 0, 0, 0);

    v4d acc0 = {0., 0., 0., 0.}, acc1 = {0., 0., 0., 0.};
    double sumsq = 0.0, psq0 = 0.0, psq1 = 0.0;

    // fixed per-lane row pointers; per chunk the lane reads 16 contiguous floats
    const float* xrow  = x     + (size_t)(tok0 + ttile * 16 + arow) * DIM + kbase;
    const float* p0row = proto + (size_t)(epair * 32 + arow)        * DIM + kbase;
    const float* p1row = proto + (size_t)(epair * 32 + 16 + arow)   * DIM + kbase;

    float4 ax[4], b0x[4], b1x[4];   // buffer X (even chunks)
    float4 ay[4], b0y[4], b1y[4];   // buffer Y (odd chunks)

#define LOADSET(A, B0, B1, c) do {                                  \
    const int _off = (c) * KC;                                      \
    _Pragma("unroll")                                               \
    for (int q = 0; q < 4; ++q) {                                   \
        A[q]  = *(const float4*)(xrow  + _off + 4 * q);             \
        B0[q] = *(const float4*)(p0row + _off + 4 * q);             \
        B1[q] = *(const float4*)(p1row + _off + 4 * q);             \
    } } while (0)

#define COMPUTE(A, B0, B1) do {                                     \
    _Pragma("unroll")                                               \
    for (int q = 0; q < 4; ++q) {                                   \
        double a0 = (double)A[q].x,  a1 = (double)A[q].y,           \
               a2 = (double)A[q].z,  a3 = (double)A[q].w;           \
        double u0 = (double)B0[q].x, u1 = (double)B0[q].y,          \
               u2 = (double)B0[q].z, u3 = (double)B0[q].w;          \
        double v0 = (double)B1[q].x, v1 = (double)B1[q].y,          \
               v2 = (double)B1[q].z, v3 = (double)B1[q].w;          \
        sumsq += a0*a0 + a1*a1 + a2*a2 + a3*a3;                     \
        psq0  += u0*u0 + u1*u1 + u2*u2 + u3*u3;                     \
        psq1  += v0*v0 + v1*v1 + v2*v2 + v3*v3;                     \
        acc0 = __builtin_amdgcn_mfma_f64_16x16x4f64(a0, u0, acc0, 0, 0, 0); \
        acc1 = __builtin_amdgcn_mfma_f64_16x16x4f64(a0, v0, acc1, 0, 0, 0); \
        acc0 = __builtin_amdgcn_mfma_f64_16x16x4f64(a1, u1, acc0, 0, 0, 0); \
        acc1 = __builtin_amdgcn_mfma_f64_16x16x4f64(a1, v1, acc1, 0, 0, 0); \
        acc0 = __builtin_amdgcn_mfma_f64_16x16x4f64(a2, u2, acc0, 0, 0, 0); \
        acc1 = __builtin_amdgcn_mfma_f64_16x16x4f64(a2, v2, acc1, 0, 0, 0); \
        acc0 = __builtin_amdgcn_mfma_f64_16x16x4f64(a3, u3, acc0, 0, 0, 0); \
        acc1 = __builtin_amdgcn_mfma_f64_16x16x4f64(a3, v3, acc1, 0, 0, 0); \
    } } while (0)

    // ---- barrier-free main loop, unroll-by-2 with named buffers ----
    LOADSET(ax, b0x, b1x, 0);
    for (int c = 0; c < NCHUNK; c += 2) {
        LOADSET(ay, b0y, b1y, c + 1);              // prefetch odd chunk
        COMPUTE(ax, b0x, b1x);                     // compute even chunk
        if (c + 2 < NCHUNK) LOADSET(ax, b0x, b1x, c + 2);
        COMPUTE(ay, b0y, b1y);                     // compute odd chunk
    }

    // ---- norms: butterfly-reduce over the 4 k-quarters (deterministic) ----
    sumsq += __shfl_xor(sumsq, 16, 64);
    sumsq += __shfl_xor(sumsq, 32, 64);
    psq0  += __shfl_xor(psq0, 16, 64);
    psq0  += __shfl_xor(psq0, 32, 64);
    psq1  += __shfl_xor(psq1, 16, 64);
    psq1  += __shfl_xor(psq1, 32, 64);
    if (akg == 0) {   // duplicate waves write identical bits -> benign
        xinv_lds[ttile * 16 + arow]      = 1.0 / fmax(sqrt(sumsq), 1e-12);
        pinv_lds[epair * 32 + arow]      = 1.0 / fmax(sqrt(psq0), 1e-12);
        pinv_lds[epair * 32 + 16 + arow] = 1.0 / fmax(sqrt(psq1), 1e-12);
    }
    __syncthreads();

    // ---- scale to cosine logits via calibrated labels, cast fp32, reshard ----
#pragma unroll
    for (int i = 0; i < 4; ++i) {
        const int tr = (int)(c1[i] * 0.25);      // true token-within-tile label
        const int ec = (int)(c2[i] * 0.25);      // true expert-within-16 label
        const int tl = ttile * 16 + tr;
        const double xi = xinv_lds[tl];
        const int e0 = epair * 32 + ec;
        const int e1 = epair * 32 + 16 + ec;
        logits[tl][e0] = (float)(acc0[i] * xi * pinv_lds[e0]);
        logits[tl][e1] = (float)(acc1[i] * xi * pinv_lds[e1]);
    }
    __syncthreads();

    // ---- epilogue: np fp32 softmax bit-chain + rank by (w32 desc, idx asc) ----
#pragma unroll 1
    for (int i = 0; i < 8; ++i) {
        const int tl = w * 8 + i;
        const float l32 = logits[tl][lane];

        float m = l32;
#pragma unroll
        for (int d = 1; d < 64; d <<= 1) {
            float o = __shfl_xor(m, d, 64);
            m = fmaxf(m, o);
        }
        const float dd = l32 - m;
        const float e32 = (float)exp((double)dd);

        // numpy pairwise_sum (n=64): 8 accumulators over stride 8
        float r[8];
#pragma unroll
        for (int j = 0; j < 8; ++j) {
            float rj = __shfl(e32, j, 64);
#pragma unroll
            for (int b = 1; b < 8; ++b)
                rj += __shfl(e32, j + 8 * b, 64);
            r[j] = rj;
        }
        const float S = ((r[0] + r[1]) + (r[2] + r[3])) +
                        ((r[4] + r[5]) + (r[6] + r[7]));
        const float wgt = e32 / S;

        int rank = 0;
#pragma unroll 1
        for (int sdist = 1; sdist < 64; ++sdist) {
            float ow = __shfl_xor(wgt, sdist, 64);
            int j = lane ^ sdist;
            rank += (ow > wgt) || (ow == wgt && j < lane);
        }

        if (rank < TOPK) {
            const int tok = tok0 + tl;
            out[tok * TOPK + rank] = wgt;                       // routing_weights
            out[NTOK * TOPK + tok * TOPK + rank] = (float)lane; // selected_experts
        }
    }
}

extern "C" void kernel_launch(void* const* d_in, const int* in_sizes, int n_in,
                              void* d_out, int out_size, void* d_ws, size_t ws_size,
                              hipStream_t stream) {
    const float* x     = (const float*)d_in[0];
    const float* proto = (const float*)d_in[1];
    float* out         = (float*)d_out;
    (void)d_ws; (void)ws_size; (void)in_sizes; (void)n_in; (void)out_size;

    router_kernel<<<NTOK / TB, 256, 0, stream>>>(x, proto, out);
}